// Round 1
// baseline (39.533 us; speedup 1.0000x reference)
//
#include <hip/hip_runtime.h>
#include <math.h>

namespace {

constexpr int NLAY = 10;
constexpr int NQB  = 4;
constexpr int NB   = 16;   // batch
constexpr int HH   = 128;
constexpr int WW   = 128;
constexpr int DI   = HH - 1;   // 127
constexpr int DJ   = WW - 1;   // 127
constexpr int NPATCH = NB * DI * DJ;   // 258064

// Combined CZ(0,1)*CZ(2,3)*CZ(1,2) sign per basis index (bit3=a,...,bit0=d):
// negative where (a&b)^(c&d)^(b&c) == 1  -> idx {3,6,11,12,13,15}
constexpr unsigned SIGNMASK = 0xB848u;

__device__ __forceinline__ float2 cmul(float2 a, float2 b) {
    return make_float2(fmaf(a.x, b.x, -a.y * b.y), fmaf(a.x, b.y, a.y * b.x));
}
__device__ __forceinline__ float2 cadd(float2 a, float2 b) {
    return make_float2(a.x + b.x, a.y + b.y);
}
__device__ __forceinline__ void mm2(float2* D, const float2* A, const float2* B) {
    D[0] = cadd(cmul(A[0], B[0]), cmul(A[1], B[2]));
    D[1] = cadd(cmul(A[0], B[1]), cmul(A[1], B[3]));
    D[2] = cadd(cmul(A[2], B[0]), cmul(A[3], B[2]));
    D[3] = cadd(cmul(A[2], B[1]), cmul(A[3], B[3]));
}

__global__ __launch_bounds__(256) void qcnn_kernel(
    const float* __restrict__ images,   // [16,128,128,3]
    const float* __restrict__ gates,    // [10,4,3] one-hot
    const float* __restrict__ angles,   // [10,4]
    float* __restrict__ out)            // [16,127,127,4]
{
    __shared__ float2 Ush[NLAY * NQB][4];   // row-major 2x2 complex per (l,q)

    const int t = threadIdx.x;

    // ---- per-block: build the 40 single-qubit unitaries U = RZ*RY*RX ----
    if (t < NLAY * NQB) {
        const float ang = angles[t];
        const float ax = gates[t * 3 + 0] * ang * 0.5f;
        const float ay = gates[t * 3 + 1] * ang * 0.5f;
        const float az = gates[t * 3 + 2] * ang * 0.5f;
        float sx, cx, sy, cy, sz, cz;
        sincosf(ax, &sx, &cx);
        sincosf(ay, &sy, &cy);
        sincosf(az, &sz, &cz);
        float2 RX[4] = {{cx, 0.f}, {0.f, -sx}, {0.f, -sx}, {cx, 0.f}};
        float2 RY[4] = {{cy, 0.f}, {-sy, 0.f}, {sy, 0.f}, {cy, 0.f}};
        float2 RZ[4] = {{cz, -sz}, {0.f, 0.f}, {0.f, 0.f}, {cz, sz}};
        float2 M[4], U[4];
        mm2(M, RY, RX);
        mm2(U, RZ, M);
        Ush[t][0] = U[0];
        Ush[t][1] = U[1];
        Ush[t][2] = U[2];
        Ush[t][3] = U[3];
    }
    __syncthreads();

    const int n = blockIdx.x * blockDim.x + t;
    if (n >= NPATCH) return;

    // patch coordinates
    const int bimg = n / (DI * DJ);
    const int rem  = n - bimg * (DI * DJ);
    const int pi   = rem / DJ;
    const int pj   = rem - pi * DJ;

    const float* base = images + ((size_t)(bimg * HH + pi) * WW + pj) * 3;

    // ---- per-qubit initial states from pixel RGB ----
    float2 S[NQB][2];
#pragma unroll
    for (int a = 0; a < 2; ++a) {
#pragma unroll
        for (int b = 0; b < 2; ++b) {
            const float* px = base + ((size_t)a * WW + b) * 3;
            const float d0 = px[0], d1 = px[1], d2 = px[2];
            // phi=pi*d0, theta=pi*d1, omega=pi*d2
            const float al = 0.5f * (d0 + d2);   // (phi+omega)/(2*pi)
            const float be = 0.5f * (d2 - d0);   // (omega-phi)/(2*pi)
            const float th = 0.5f * d1;          // theta/(2*pi)
            float sa, ca, sb, cb, stt, ctt;
            sincospif(al, &sa, &ca);
            sincospif(be, &sb, &cb);
            sincospif(th, &stt, &ctt);
            const int q = a * 2 + b;
            S[q][0] = make_float2(ca * ctt, -sa * ctt);   // exp(-i*pi*al)*cos
            S[q][1] = make_float2(cb * stt,  sb * stt);   // exp(+i*pi*be)*sin
        }
    }

    // ---- product state: st[a*8+b*4+c*2+d] ----
    float2 st[16];
#pragma unroll
    for (int a = 0; a < 2; ++a) {
#pragma unroll
        for (int b = 0; b < 2; ++b) {
            const float2 ab = cmul(S[0][a], S[1][b]);
#pragma unroll
            for (int c = 0; c < 2; ++c) {
                const float2 abc = cmul(ab, S[2][c]);
#pragma unroll
                for (int d = 0; d < 2; ++d) {
                    st[a * 8 + b * 4 + c * 2 + d] = cmul(abc, S[3][d]);
                }
            }
        }
    }

    // ---- circuit layers ----
#pragma unroll 1
    for (int l = 0; l < NLAY; ++l) {
#pragma unroll
        for (int q = 0; q < NQB; ++q) {
            const float2 u00 = Ush[l * NQB + q][0];
            const float2 u01 = Ush[l * NQB + q][1];
            const float2 u10 = Ush[l * NQB + q][2];
            const float2 u11 = Ush[l * NQB + q][3];
            const int s = 8 >> q;
#pragma unroll
            for (int p = 0; p < 8; ++p) {
                const int i0 = ((p & ~(s - 1)) << 1) | (p & (s - 1));
                const int i1 = i0 + s;
                const float2 va = st[i0];
                const float2 vb = st[i1];
                st[i0] = cadd(cmul(u00, va), cmul(u01, vb));
                st[i1] = cadd(cmul(u10, va), cmul(u11, vb));
            }
        }
        // fused CZ(0,1), CZ(2,3), CZ(1,2) sign flips
#pragma unroll
        for (int k = 0; k < 16; ++k) {
            if ((SIGNMASK >> k) & 1u) {
                st[k].x = -st[k].x;
                st[k].y = -st[k].y;
            }
        }
    }

    // ---- expectations <Z_i> ----
    float e0 = 0.f, e1 = 0.f, e2 = 0.f, e3 = 0.f;
#pragma unroll
    for (int k = 0; k < 16; ++k) {
        const float pr = fmaf(st[k].x, st[k].x, st[k].y * st[k].y);
        e0 += (k & 8) ? -pr : pr;
        e1 += (k & 4) ? -pr : pr;
        e2 += (k & 2) ? -pr : pr;
        e3 += (k & 1) ? -pr : pr;
    }

    float4 o = make_float4(e0, e1, e2, e3);
    *reinterpret_cast<float4*>(out + (size_t)n * 4) = o;
}

}  // namespace

extern "C" void kernel_launch(void* const* d_in, const int* in_sizes, int n_in,
                              void* d_out, int out_size, void* d_ws, size_t ws_size,
                              hipStream_t stream) {
    const float* images = (const float*)d_in[0];
    const float* gates  = (const float*)d_in[1];
    const float* angles = (const float*)d_in[2];
    float* out = (float*)d_out;

    const int block = 256;
    const int grid = (NPATCH + block - 1) / block;
    qcnn_kernel<<<grid, block, 0, stream>>>(images, gates, angles, out);
}